// Round 11
// baseline (436.685 us; speedup 1.0000x reference)
//
#include <hip/hip_runtime.h>
#include <math.h>

#define T_TOK 32768
#define D_DIM 128
#define K_CODE 8192
#define BM 256              // tokens per block (argmin): 4 waves x 64
#define BN 64               // codes per block (argmin)

typedef unsigned long long ull;
typedef _Float16 v8h __attribute__((ext_vector_type(8)));
typedef _Float16 v4h __attribute__((ext_vector_type(4)));
typedef float v16f __attribute__((ext_vector_type(16)));

#define SCALE 4096.0f        // 2^12: pushes f16 split residuals into normal range
#define DESCALE (1.0f / 4096.0f)
#define ACC_SCALE (-0x1p-23f)   // s = (zn+cn) - 2*dot, dot = acc*2^-24

// Cpack layout (bytes): [cb=code/64][ (s*2+mt)*8+kc ][lane64][j8 f16]
// Zpack layout (bytes): [tb=token/32][ s ][ kc ][lane64][j8 f16]

// ---------------- fused prep: proj(+cn) | prep_z(+zn+inits) ----------------
// Path A (bid < 2048): 4 waves x 1 code row each — per-wave math bit-identical
// to the R8-R10 proj kernel. Path B: prep_z (identical), then znorm re-loading
// z with the OLD per-token lane layout (bit-identical zn), then inits.
__global__ __launch_bounds__(256) void prep_kernel(const float* __restrict__ E,
                                                   const float* __restrict__ W,
                                                   const float* __restrict__ b,
                                                   const float* __restrict__ Z,
                                                   char* __restrict__ Cpack,
                                                   float* __restrict__ cn,
                                                   char* __restrict__ Zpack,
                                                   float* __restrict__ zn,
                                                   ull* __restrict__ packed,
                                                   int* __restrict__ counts,
                                                   float* __restrict__ loss) {
    int bid = blockIdx.x;
    int tid = threadIdx.x;
    int lane = tid & 63;
    int w = tid >> 6;

    if (bid < 2048) {
        // ---------------- proj path: code r = bid*4 + w ----------------
        int r = bid * 4 + w;
        int l = lane;
        const float4* E4 = (const float4*)(E + (size_t)r * D_DIM);
        const float4* WA = (const float4*)(W + (size_t)l * D_DIM);
        const float4* WB = (const float4*)(W + (size_t)(l + 64) * D_DIM);

        float4 aA = make_float4(0.f, 0.f, 0.f, 0.f);
        float4 aB = make_float4(0.f, 0.f, 0.f, 0.f);
#pragma unroll
        for (int dd = 0; dd < 32; ++dd) {
            float4 e = E4[dd];
            float4 wa = WA[dd], wb = WB[dd];
            aA.x = fmaf(e.x, wa.x, aA.x);
            aA.y = fmaf(e.y, wa.y, aA.y);
            aA.z = fmaf(e.z, wa.z, aA.z);
            aA.w = fmaf(e.w, wa.w, aA.w);
            aB.x = fmaf(e.x, wb.x, aB.x);
            aB.y = fmaf(e.y, wb.y, aB.y);
            aB.z = fmaf(e.z, wb.z, aB.z);
            aB.w = fmaf(e.w, wb.w, aB.w);
        }
        float vA = ((aA.x + aA.y) + (aA.z + aA.w)) + b[l];
        float vB = ((aB.x + aB.y) + (aB.z + aB.w)) + b[l + 64];

        char* cp = Cpack + (size_t)(r >> 6) * 32768;
        int mt = (r >> 5) & 1, rs = r & 31;
        {   // d = l
            int kc = l >> 4, hf = (l >> 3) & 1, j = l & 7;
            float f = vA * SCALE;
            _Float16 h = (_Float16)f;
            _Float16 m = (_Float16)(f - (float)h);
            size_t off = (size_t)((mt * 8 + kc) * 1024 + (hf * 32 + rs) * 16 + j * 2);
            *(_Float16*)(cp + off) = h;
            *(_Float16*)(cp + off + 16384) = m;
        }
        {   // d = l + 64
            int d = l + 64;
            int kc = d >> 4, hf = (d >> 3) & 1, j = d & 7;
            float f = vB * SCALE;
            _Float16 h = (_Float16)f;
            _Float16 m = (_Float16)(f - (float)h);
            size_t off = (size_t)((mt * 8 + kc) * 1024 + (hf * 32 + rs) * 16 + j * 2);
            *(_Float16*)(cp + off) = h;
            *(_Float16*)(cp + off + 16384) = m;
        }

        float s = vA * vA + vB * vB;
#pragma unroll
        for (int off = 32; off > 0; off >>= 1) s += __shfl_down(s, off, 64);
        if (l == 0) cn[r] = s;
    } else {
        // ---------------- prep_z path: 32-token group tb ----------------
        int tb = bid - 2048;
        char* zp = Zpack + (size_t)tb * 16384;
#pragma unroll
        for (int kq = 0; kq < 2; ++kq) {
            int kc = 2 * w + kq;
            const float* src = Z + (size_t)(tb * 32 + (lane & 31)) * D_DIM
                                 + kc * 16 + (lane >> 5) * 8;
            float4 a = *(const float4*)(src);
            float4 c = *(const float4*)(src + 4);
            float vals[8] = {a.x, a.y, a.z, a.w, c.x, c.y, c.z, c.w};
            v8h h, m;
#pragma unroll
            for (int j = 0; j < 8; ++j) {
                float f = vals[j] * SCALE;
                _Float16 hh = (_Float16)f;
                h[j] = hh;
                m[j] = (_Float16)(f - (float)hh);
            }
            *(v8h*)(zp + (size_t)(kc * 1024 + lane * 16)) = h;
            *(v8h*)(zp + (size_t)(8192 + kc * 1024 + lane * 16)) = m;
        }
        // znorm: wave w -> tokens tb*32 + 8w .. +7, OLD per-token lane layout
        // (lane l: a=z[t][l], b=z[t][64+l], same shfl chain) -> zn bit-identical
#pragma unroll
        for (int i = 0; i < 8; ++i) {
            int t = tb * 32 + 8 * w + i;
            float a = Z[(size_t)t * D_DIM + lane];
            float b2 = Z[(size_t)t * D_DIM + 64 + lane];
            float s = a * a + b2 * b2;
#pragma unroll
            for (int off = 32; off > 0; off >>= 1) s += __shfl_down(s, off, 64);
            if (lane == 0) {
                zn[t] = s;
                packed[t] = ~0ull;
            }
        }
        // inits: counts (first 32 prep blocks cover 8192) + loss
        if (tb < 32) counts[tb * 256 + tid] = 0;
        if (tb == 32 && tid == 0) loss[0] = 0.f;
    }
}

// ---------------- MFMA argmin (nt=2, A ds-dbuf + B 2-ahead ring) ----------
// Corrected model: MFMA "8 cyc" is per-CU -> no pipe is BW-bound here; the
// 45% MfmaUtil ceiling was wave-serial latency (per-kc lgkm wait on A
// ds_reads, VALU overhead, low occupancy). Fix: A prefetched one kc ahead
// (all-immediate ds offsets), B prefetched two kc ahead, nt=2 + (256,3).
__global__ __launch_bounds__(256, 3) void argmin_kernel(const char* __restrict__ Zpack,
                                                        const char* __restrict__ Cpack,
                                                        const float* __restrict__ cn,
                                                        const float* __restrict__ zn,
                                                        ull* __restrict__ packed) {
    __shared__ char lds[33024];   // 32768 A-pack + 256 cn

    int tid = threadIdx.x;
    int lane = tid & 63;
    int w = __builtin_amdgcn_readfirstlane(tid >> 6);
    int cb = blockIdx.x;          // x fastest -> consecutive blocks share tokens
    int nb = cb * BN;
    int mb = blockIdx.y * BM;

    // ---- stage code pack (contiguous 32 KB) + cn slice ----
    {
        const float4* src = (const float4*)(Cpack + (size_t)cb * 32768);
        float4* dst = (float4*)lds;
#pragma unroll
        for (int it = 0; it < 8; ++it) dst[it * 256 + tid] = src[it * 256 + tid];
        if (tid < 64) *(float*)(lds + 32768 + tid * 4) = cn[nb + tid];
    }
    __syncthreads();

    v16f acc[2][2];               // [mt codes][nt tokens]
#pragma unroll
    for (int mt = 0; mt < 2; ++mt)
#pragma unroll
        for (int nt = 0; nt < 2; ++nt) acc[mt][nt] = (v16f)0.f;

    // wave w owns tokens [mb+64w, mb+64w+64)
    int tb0 = (mb >> 5) + 2 * w;
    const char* zb00 = Zpack + (size_t)tb0 * 16384 + lane * 16;          // nt0,h
    const char* zb01 = zb00 + 8192;                                      // nt0,m
    const char* zb10 = Zpack + (size_t)(tb0 + 1) * 16384 + lane * 16;    // nt1,h
    const char* zb11 = zb10 + 8192;                                      // nt1,m
    const char* ab = lds + lane * 16;

    // B ring, 2 kc deep: B[kc&1] = {Bh0, Bm0, Bh1, Bm1} for that kc.
    v8h Bring[2][4];
    Bring[0][0] = *(const v8h*)(zb00);
    Bring[0][1] = *(const v8h*)(zb01);
    Bring[0][2] = *(const v8h*)(zb10);
    Bring[0][3] = *(const v8h*)(zb11);
    Bring[1][0] = *(const v8h*)(zb00 + 1024);
    Bring[1][1] = *(const v8h*)(zb01 + 1024);
    Bring[1][2] = *(const v8h*)(zb10 + 1024);
    Bring[1][3] = *(const v8h*)(zb11 + 1024);

    // A dbuf: Aring[kc&1] = {Ah0, Ah1, Am0, Am1}; ds offsets all immediates.
    v8h Aring[2][4];
#pragma unroll
    for (int s = 0; s < 4; ++s) Aring[0][s] = *(const v8h*)(ab + (s * 8) * 1024);

#pragma unroll
    for (int kc = 0; kc < 8; ++kc) {
        const int cur = kc & 1;
        const int nxt = cur ^ 1;
        // bind current operands FIRST (full unroll -> pure register renaming)
        v8h Ah0 = Aring[cur][0], Ah1 = Aring[cur][1];
        v8h Am0 = Aring[cur][2], Am1 = Aring[cur][3];
        v8h Bh0 = Bring[cur][0], Bm0 = Bring[cur][1];
        v8h Bh1 = Bring[cur][2], Bm1 = Bring[cur][3];

        if (kc < 7) {   // prefetch next kc's A-frags (immediate ds offsets)
#pragma unroll
            for (int s = 0; s < 4; ++s)
                Aring[nxt][s] = *(const v8h*)(ab + (s * 8 + kc + 1) * 1024);
        }
        if (kc < 6) {   // prefetch kc+2's B-frags into the freed slot
            Bring[cur][0] = *(const v8h*)(zb00 + (kc + 2) * 1024);
            Bring[cur][1] = *(const v8h*)(zb01 + (kc + 2) * 1024);
            Bring[cur][2] = *(const v8h*)(zb10 + (kc + 2) * 1024);
            Bring[cur][3] = *(const v8h*)(zb11 + (kc + 2) * 1024);
        }

        // pass h*h
        acc[0][0] = __builtin_amdgcn_mfma_f32_32x32x16_f16(Ah0, Bh0, acc[0][0], 0, 0, 0);
        acc[0][1] = __builtin_amdgcn_mfma_f32_32x32x16_f16(Ah0, Bh1, acc[0][1], 0, 0, 0);
        acc[1][0] = __builtin_amdgcn_mfma_f32_32x32x16_f16(Ah1, Bh0, acc[1][0], 0, 0, 0);
        acc[1][1] = __builtin_amdgcn_mfma_f32_32x32x16_f16(Ah1, Bh1, acc[1][1], 0, 0, 0);
        // pass h*m
        acc[0][0] = __builtin_amdgcn_mfma_f32_32x32x16_f16(Ah0, Bm0, acc[0][0], 0, 0, 0);
        acc[0][1] = __builtin_amdgcn_mfma_f32_32x32x16_f16(Ah0, Bm1, acc[0][1], 0, 0, 0);
        acc[1][0] = __builtin_amdgcn_mfma_f32_32x32x16_f16(Ah1, Bm0, acc[1][0], 0, 0, 0);
        acc[1][1] = __builtin_amdgcn_mfma_f32_32x32x16_f16(Ah1, Bm1, acc[1][1], 0, 0, 0);
        // pass m*h
        acc[0][0] = __builtin_amdgcn_mfma_f32_32x32x16_f16(Am0, Bh0, acc[0][0], 0, 0, 0);
        acc[0][1] = __builtin_amdgcn_mfma_f32_32x32x16_f16(Am0, Bh1, acc[0][1], 0, 0, 0);
        acc[1][0] = __builtin_amdgcn_mfma_f32_32x32x16_f16(Am1, Bh0, acc[1][0], 0, 0, 0);
        acc[1][1] = __builtin_amdgcn_mfma_f32_32x32x16_f16(Am1, Bh1, acc[1][1], 0, 0, 0);
    }

    // ---- epilogue: in-lane argmin over this block's 64 codes (as R9) ----
    const float* cn_s = (const float*)(lds + 32768);
    int half_id = lane >> 5;
    int tok0 = mb + w * 64 + (lane & 31);   // nt=0
    int tok1 = tok0 + 32;                   // nt=1
    float zn0 = zn[tok0], zn1 = zn[tok1];

    float best0 = 3.4e38f, best1 = 3.4e38f;
    int bi0 = nb, bi1 = nb;
#pragma unroll
    for (int mt = 0; mt < 2; ++mt) {
#pragma unroll
        for (int reg = 0; reg < 16; ++reg) {
            // ascending code order within half -> strict < keeps first-min
            int mrow = 32 * mt + (reg & 3) + 8 * (reg >> 2) + 4 * half_id;
            float cnv = cn_s[mrow];
            int code = nb + mrow;
            // s = (zn + cn) - 2*dot ; dot = acc*2^-24 (exact scale), fused:
            float s0 = fmaf(acc[mt][0][reg], ACC_SCALE, zn0 + cnv);
            float s1 = fmaf(acc[mt][1][reg], ACC_SCALE, zn1 + cnv);
            if (s0 < best0) { best0 = s0; bi0 = code; }
            if (s1 < best1) { best1 = s1; bi1 = code; }
        }
    }
    // cross-half combine with explicit smaller-idx tie-break
    {
        float ob = __shfl_xor(best0, 32, 64);
        int oi = __shfl_xor(bi0, 32, 64);
        if (ob < best0 || (ob == best0 && oi < bi0)) { best0 = ob; bi0 = oi; }
        ob = __shfl_xor(best1, 32, 64);
        oi = __shfl_xor(bi1, 32, 64);
        if (ob < best1 || (ob == best1 && oi < bi1)) { best1 = ob; bi1 = oi; }
    }
    // d > 0 -> f32 bits monotone as uint; idx in low bits -> first-min ties
    if (half_id == 0) {
        ull pk = ((ull)__float_as_uint(best0) << 32) | (unsigned)bi0;
        atomicMin(&packed[tok0], pk);
    } else {
        ull pk = ((ull)__float_as_uint(best1) << 32) | (unsigned)bi1;
        atomicMin(&packed[tok1], pk);
    }
}

// ---------------- zq: unpack winner, reconstruct code row, out + counts + loss
__global__ __launch_bounds__(256) void zq_kernel(const float* __restrict__ Z,
                                                 const char* __restrict__ Cpack,
                                                 const ull* __restrict__ packed,
                                                 float* __restrict__ out,
                                                 int* __restrict__ counts,
                                                 float* __restrict__ loss) {
    int gid = blockIdx.x * 256 + threadIdx.x;   // over T*D/4 float4s
    int t = gid >> 5;                           // 32 float4 per token
    int d4 = gid & 31;
    int idx = (int)(packed[t] & 0xFFFFFFFFull);
    if (d4 == 0) atomicAdd(&counts[idx], 1);

    // reconstruct c[d0..d0+3] = (ch + cm) * 2^-12 (exact sum: spans < 24 bits)
    int d0 = 4 * d4;
    int kc = d0 >> 4, hf = (d0 >> 3) & 1, j0 = d0 & 7;
    const char* cp = Cpack + (size_t)(idx >> 6) * 32768
                   + (size_t)((((idx >> 5) & 1) * 8 + kc) * 1024
                              + (hf * 32 + (idx & 31)) * 16 + j0 * 2);
    v4h h = *(const v4h*)(cp);
    v4h m = *(const v4h*)(cp + 16384);
    float4 cv;
    cv.x = ((float)h[0] + (float)m[0]) * DESCALE;
    cv.y = ((float)h[1] + (float)m[1]) * DESCALE;
    cv.z = ((float)h[2] + (float)m[2]) * DESCALE;
    cv.w = ((float)h[3] + (float)m[3]) * DESCALE;

    float4 zv = ((const float4*)Z)[gid];
    float dx = cv.x - zv.x, dy = cv.y - zv.y, dz = cv.z - zv.z, dw = cv.w - zv.w;
    float4 o;
    o.x = zv.x + dx;    // z + (z_q - z): match reference elementwise rounding
    o.y = zv.y + dy;
    o.z = zv.z + dz;
    o.w = zv.w + dw;
    ((float4*)out)[gid] = o;

    float ls = dx * dx + dy * dy + dz * dz + dw * dw;
#pragma unroll
    for (int off = 32; off > 0; off >>= 1) ls += __shfl_down(ls, off, 64);
    __shared__ float red[4];
    int lane = threadIdx.x & 63, w = threadIdx.x >> 6;
    if (lane == 0) red[w] = ls;
    __syncthreads();
    if (threadIdx.x == 0) {
        atomicAdd(loss, (red[0] + red[1]) + (red[2] + red[3]));
    }
}

// ---------------- scalars: commit_loss, perplexity ----------------
__global__ __launch_bounds__(256) void scalars_kernel(const int* __restrict__ counts,
                                                      const float* __restrict__ loss,
                                                      float* __restrict__ out) {
    float s = 0.f;
    for (int i = threadIdx.x; i < K_CODE; i += 256) {
        float e = (float)counts[i] * (1.0f / (float)T_TOK);
        s += e * logf(e + 1e-8f);
    }
#pragma unroll
    for (int off = 32; off > 0; off >>= 1) s += __shfl_down(s, off, 64);
    __shared__ float red[4];
    int lane = threadIdx.x & 63, w = threadIdx.x >> 6;
    if (lane == 0) red[w] = s;
    __syncthreads();
    if (threadIdx.x == 0) {
        float ssum = (red[0] + red[1]) + (red[2] + red[3]);
        out[(size_t)T_TOK * D_DIM + 0] = 1.25f * loss[0] / (float)((size_t)T_TOK * D_DIM);
        out[(size_t)T_TOK * D_DIM + 1] = expf(-ssum);
    }
}

extern "C" void kernel_launch(void* const* d_in, const int* in_sizes, int n_in,
                              void* d_out, int out_size, void* d_ws, size_t ws_size,
                              hipStream_t stream) {
    const float* z   = (const float*)d_in[0];   // [8,4096,128]
    const float* emb = (const float*)d_in[1];   // [8192,128]
    const float* pw  = (const float*)d_in[2];   // [128,128]
    const float* pb  = (const float*)d_in[3];   // [128]
    float* out = (float*)d_out;

    // Zpack (f16 split fragments, 16.78 MB) lives in d_out: dead scratch until
    // zq_kernel overwrites d_out with the final z_q_st.
    char* Zpack = (char*)d_out;

    char* ws = (char*)d_ws;
    // layout (bytes):
    //   Cpack:  0        .. 4194304   (128 cb x 32768)
    //   cn:     4194304  .. 4227072   (8192 f32)
    //   zn:     4227072  .. 4358144   (32768 f32)
    //   packed: 4358144  .. 4620288   (32768 u64)
    //   counts: 4620288  .. 4653056   (8192 i32)
    //   loss:   4653056  .. 4653060   (1 f32)
    char*  Cpack  = ws + 0;
    float* cn     = (float*)(ws + 4194304);
    float* zn     = (float*)(ws + 4227072);
    ull*   packed = (ull*)  (ws + 4358144);
    int*   counts = (int*)  (ws + 4620288);
    float* loss   = (float*)(ws + 4653056);

    prep_kernel<<<3072, 256, 0, stream>>>(emb, pw, pb, z, Cpack, cn, Zpack, zn,
                                          packed, counts, loss);
    argmin_kernel<<<dim3(K_CODE / BN, T_TOK / BM), 256, 0, stream>>>(Zpack, Cpack, cn, zn, packed);
    zq_kernel<<<(T_TOK * D_DIM / 4) / 256, 256, 0, stream>>>(z, Cpack, packed, out, counts, loss);
    scalars_kernel<<<1, 256, 0, stream>>>(counts, loss, out);
}